// Round 21
// baseline (72.522 us; speedup 1.0000x reference)
//
#include <hip/hip_runtime.h>

#define N_NODES 50000
#define DIM 64
#define NPB 32                                  // nodes per bucket (dst >> 5)
#define NB 1563                                 // ceil(50000/32)
#define NCHUNK 128                              // edge chunks (= binning blocks)
#define CAPB 1024                               // fixed packed capacity per bucket
#define CAP 1024                                // == CAPB -> aggregate is single-pass

typedef unsigned short ushort_t;

__device__ __forceinline__ ushort_t f32_to_bf16(float f) {
    unsigned u = __float_as_uint(f);
    u += 0x7FFFu + ((u >> 16) & 1u);            // round-to-nearest-even
    return (ushort_t)(u >> 16);
}

__device__ __forceinline__ void acc_pair(float& a0, float& a1, unsigned u) {
    a0 += __uint_as_float(u << 16);             // low bf16  (even dim)
    a1 += __uint_as_float(u & 0xFFFF0000u);     // high bf16 (odd dim)
}

// ---- K0: init per-bucket cursors to region bases (tiny) ----
__global__ void init_cursor_kernel(int* __restrict__ cursor) {
    int t = blockIdx.x * blockDim.x + threadIdx.x;
    if (t <= NB) cursor[t] = t * CAPB;
}

// ---- K1: fused convert(x->bf16, NT both ways) + hist + reserve + scatter ----
__global__ void binning_kernel(const float* __restrict__ xf,
                               ushort_t* __restrict__ xh,
                               const int* __restrict__ row,
                               const int* __restrict__ col,
                               int* __restrict__ cursor,
                               unsigned* __restrict__ packed,
                               int E, int chunk, int n4) {
    __shared__ int h[NB];
    __shared__ int lcur[NB];
    int c = blockIdx.x;
    int tid = threadIdx.x;
    // convert: grid-stride; NT load (xf read-once) + NT store (xh -> LLC so
    // remote-XCD gathers don't hit dirty-L2 lines)
    for (int i = c * blockDim.x + tid; i < n4; i += gridDim.x * blockDim.x) {
        const float* xp = xf + (size_t)i * 4;
        float vx = __builtin_nontemporal_load(xp + 0);
        float vy = __builtin_nontemporal_load(xp + 1);
        float vz = __builtin_nontemporal_load(xp + 2);
        float vw = __builtin_nontemporal_load(xp + 3);
        unsigned lo = (unsigned)f32_to_bf16(vx) | ((unsigned)f32_to_bf16(vy) << 16);
        unsigned hi = (unsigned)f32_to_bf16(vz) | ((unsigned)f32_to_bf16(vw) << 16);
        unsigned* hp = reinterpret_cast<unsigned*>(xh + (size_t)i * 4);
        __builtin_nontemporal_store(lo, hp + 0);
        __builtin_nontemporal_store(hi, hp + 1);
    }
    for (int b = tid; b < NB; b += blockDim.x) h[b] = 0;
    __syncthreads();
    int beg = c * chunk, end = min(beg + chunk, E);
    int nfull = (end - beg) >> 2;
    for (int g = tid; g < nfull; g += blockDim.x) {
        int4 c4 = *reinterpret_cast<const int4*>(col + beg + g * 4);
        atomicAdd(&h[c4.x >> 5], 1);
        atomicAdd(&h[c4.y >> 5], 1);
        atomicAdd(&h[c4.z >> 5], 1);
        atomicAdd(&h[c4.w >> 5], 1);
    }
    for (int e = beg + nfull * 4 + tid; e < end; e += blockDim.x)
        atomicAdd(&h[col[e] >> 5], 1);
    __syncthreads();
    for (int b = tid; b < NB; b += blockDim.x) {
        int v = h[b];
        lcur[b] = (v > 0) ? atomicAdd(&cursor[b], v) : 0;   // reserve block slice
    }
    __syncthreads();
    for (int g = tid; g < nfull; g += blockDim.x) {
        int e = beg + g * 4;
        int4 d4 = *reinterpret_cast<const int4*>(col + e);
        int4 s4 = *reinterpret_cast<const int4*>(row + e);
        int p0 = atomicAdd(&lcur[d4.x >> 5], 1);
        __builtin_nontemporal_store((unsigned)s4.x | ((unsigned)(d4.x & 31) << 16), packed + p0);
        int p1 = atomicAdd(&lcur[d4.y >> 5], 1);
        __builtin_nontemporal_store((unsigned)s4.y | ((unsigned)(d4.y & 31) << 16), packed + p1);
        int p2 = atomicAdd(&lcur[d4.z >> 5], 1);
        __builtin_nontemporal_store((unsigned)s4.z | ((unsigned)(d4.z & 31) << 16), packed + p2);
        int p3 = atomicAdd(&lcur[d4.w >> 5], 1);
        __builtin_nontemporal_store((unsigned)s4.w | ((unsigned)(d4.w & 31) << 16), packed + p3);
    }
    for (int e = beg + nfull * 4 + tid; e < end; e += blockDim.x) {
        int d = col[e];
        int p = atomicAdd(&lcur[d >> 5], 1);
        __builtin_nontemporal_store((unsigned)row[e] | ((unsigned)(d & 31) << 16), packed + p);
    }
}

// ---- K2: single-pass per-bucket counting sort + 8-lane/row gather + mean ----
// packed register-staged via NT loads; out written with NT stores.
template <bool BF16>
__global__ __launch_bounds__(512)
void aggregate_bucket_kernel(const float* __restrict__ xf,
                             const ushort_t* __restrict__ xh,
                             const unsigned* __restrict__ packed,
                             const int* __restrict__ cursor,
                             float* __restrict__ out) {
    __shared__ unsigned short srcs[CAP];
    __shared__ int hist[NPB];
    __shared__ int segoff[NPB];
    __shared__ int lcur[NPB];

    int b = blockIdx.x;
    int tid = threadIdx.x;                      // 0..511
    int lane = tid & 63;
    int wv = tid >> 6;                          // wave 0..7
    int g8 = lane >> 3;                         // row slot 0..7
    int o = lane & 7;                           // dim octet (dims o*8 .. o*8+7)
    int seg_beg = b * CAPB;
    int m = cursor[b] - seg_beg;                // bucket edge count (<= CAP)
    int node_base = b * NPB;
    int nnodes = min(NPB, N_NODES - node_base);

    if (tid < NPB) hist[tid] = 0;
    __syncthreads();

    // register-stage packed (2 entries/thread, NT) + LDS histogram
    unsigned v0 = 0, v1 = 0;
    int i0 = tid, i1 = tid + 512;
    if (i0 < m) { v0 = __builtin_nontemporal_load(packed + seg_beg + i0); atomicAdd(&hist[v0 >> 16], 1); }
    if (i1 < m) { v1 = __builtin_nontemporal_load(packed + seg_beg + i1); atomicAdd(&hist[v1 >> 16], 1); }
    __syncthreads();

    if (tid < NPB) {                            // lanes 0..31 of wave 0: scan 32 bins
        int v = hist[tid];
        int incl = v;
        #pragma unroll
        for (int ofs = 1; ofs < 32; ofs <<= 1) {
            int t = __shfl_up(incl, ofs);
            if (lane >= ofs) incl += t;
        }
        segoff[tid] = incl - v;
        lcur[tid] = incl - v;
    }
    __syncthreads();

    if (i0 < m) { int p = atomicAdd(&lcur[v0 >> 16], 1); srcs[p] = (unsigned short)(v0 & 0xFFFF); }
    if (i1 < m) { int p = atomicAdd(&lcur[v1 >> 16], 1); srcs[p] = (unsigned short)(v1 & 0xFFFF); }
    __syncthreads();

    float acc[4][8];
    #pragma unroll
    for (int r = 0; r < 4; ++r)
        #pragma unroll
        for (int k = 0; k < 8; ++k) acc[r][k] = 0.0f;

    #pragma unroll
    for (int r = 0; r < 4; ++r) {
        int ln = wv * 4 + r;
        int st = segoff[ln];
        int len = hist[ln];
        int j = 0;
        for (; j + 16 <= len; j += 16) {        // 16 rows in flight per wave
            int s0 = srcs[st + j + g8];
            int s1 = srcs[st + j + 8 + g8];
            if (BF16) {
                uint4 a0 = *reinterpret_cast<const uint4*>(xh + (size_t)s0 * DIM + o * 8);
                uint4 a1 = *reinterpret_cast<const uint4*>(xh + (size_t)s1 * DIM + o * 8);
                acc_pair(acc[r][0], acc[r][1], a0.x);
                acc_pair(acc[r][2], acc[r][3], a0.y);
                acc_pair(acc[r][4], acc[r][5], a0.z);
                acc_pair(acc[r][6], acc[r][7], a0.w);
                acc_pair(acc[r][0], acc[r][1], a1.x);
                acc_pair(acc[r][2], acc[r][3], a1.y);
                acc_pair(acc[r][4], acc[r][5], a1.z);
                acc_pair(acc[r][6], acc[r][7], a1.w);
            } else {
                float4 u0 = *reinterpret_cast<const float4*>(xf + (size_t)s0 * DIM + o * 8);
                float4 u1 = *reinterpret_cast<const float4*>(xf + (size_t)s0 * DIM + o * 8 + 4);
                float4 u2 = *reinterpret_cast<const float4*>(xf + (size_t)s1 * DIM + o * 8);
                float4 u3 = *reinterpret_cast<const float4*>(xf + (size_t)s1 * DIM + o * 8 + 4);
                acc[r][0] += u0.x + u2.x; acc[r][1] += u0.y + u2.y;
                acc[r][2] += u0.z + u2.z; acc[r][3] += u0.w + u2.w;
                acc[r][4] += u1.x + u3.x; acc[r][5] += u1.y + u3.y;
                acc[r][6] += u1.z + u3.z; acc[r][7] += u1.w + u3.w;
            }
        }
        for (; j < len; j += 8) {
            if (j + g8 < len) {
                int s = srcs[st + j + g8];
                if (BF16) {
                    uint4 a0 = *reinterpret_cast<const uint4*>(xh + (size_t)s * DIM + o * 8);
                    acc_pair(acc[r][0], acc[r][1], a0.x);
                    acc_pair(acc[r][2], acc[r][3], a0.y);
                    acc_pair(acc[r][4], acc[r][5], a0.z);
                    acc_pair(acc[r][6], acc[r][7], a0.w);
                } else {
                    float4 u0 = *reinterpret_cast<const float4*>(xf + (size_t)s * DIM + o * 8);
                    float4 u1 = *reinterpret_cast<const float4*>(xf + (size_t)s * DIM + o * 8 + 4);
                    acc[r][0] += u0.x; acc[r][1] += u0.y;
                    acc[r][2] += u0.z; acc[r][3] += u0.w;
                    acc[r][4] += u1.x; acc[r][5] += u1.y;
                    acc[r][6] += u1.z; acc[r][7] += u1.w;
                }
            }
        }
    }
    __syncthreads();
    // reduce across row slots (xor 8,16,32) + mean + non-temporal store
    #pragma unroll
    for (int r = 0; r < 4; ++r) {
        int ln = wv * 4 + r;
        #pragma unroll
        for (int k = 0; k < 8; ++k) {
            acc[r][k] += __shfl_xor(acc[r][k], 8);
            acc[r][k] += __shfl_xor(acc[r][k], 16);
            acc[r][k] += __shfl_xor(acc[r][k], 32);
        }
        if (g8 == 0 && ln < nnodes) {
            int c = hist[ln];
            float inv = (c > 0) ? 1.0f / (float)c : 0.0f;
            float* op = out + (size_t)(node_base + ln) * DIM + o * 8;
            #pragma unroll
            for (int k = 0; k < 8; ++k)
                __builtin_nontemporal_store(acc[r][k] * inv, op + k);
        }
    }
}

extern "C" void kernel_launch(void* const* d_in, const int* in_sizes, int n_in,
                              void* d_out, int out_size, void* d_ws, size_t ws_size,
                              hipStream_t stream) {
    const float* x = (const float*)d_in[0];
    const int* edge_index = (const int*)d_in[1];  // [2, E] flat: row then col
    int E = in_sizes[1] / 2;
    const int* row = edge_index;
    const int* col = edge_index + E;
    float* out = (float*)d_out;

    int chunk = (((E + NCHUNK - 1) / NCHUNK) + 3) & ~3;   // multiple of 4
    int n4 = N_NODES * DIM / 4;

    // ws: cursor 1568 | packed NB*CAPB | xh N*DIM bf16
    int* cursor      = (int*)d_ws;
    unsigned* packed = (unsigned*)(cursor + 1568);
    ushort_t* xh     = (ushort_t*)(packed + (size_t)NB * CAPB);
    size_t need_bf16 = (size_t)((char*)(xh + (size_t)N_NODES * DIM) - (char*)d_ws);
    bool use_bf16 = (ws_size >= need_bf16);

    init_cursor_kernel<<<7, 256, 0, stream>>>(cursor);
    binning_kernel<<<NCHUNK, 1024, 0, stream>>>(x, xh, row, col, cursor, packed,
                                                E, chunk, use_bf16 ? n4 : 0);
    if (use_bf16)
        aggregate_bucket_kernel<true><<<NB, 512, 0, stream>>>(x, xh, packed, cursor, out);
    else
        aggregate_bucket_kernel<false><<<NB, 512, 0, stream>>>(x, xh, packed, cursor, out);
}

// Round 22
// 52.698 us; speedup vs baseline: 1.3762x; 1.3762x over previous
//
#include <hip/hip_runtime.h>

#define N_NODES 50000
#define DIM 64
#define NPB 32                                  // nodes per bucket (dst >> 5)
#define NB 1563                                 // ceil(50000/32)
#define NCHUNK 128                              // edge chunks (= binning blocks)
#define CAPB 1024                               // fixed packed capacity per bucket
#define CAP 1024                                // == CAPB -> aggregate is single-pass

typedef unsigned short ushort_t;

__device__ __forceinline__ ushort_t f32_to_bf16(float f) {
    unsigned u = __float_as_uint(f);
    u += 0x7FFFu + ((u >> 16) & 1u);            // round-to-nearest-even
    return (ushort_t)(u >> 16);
}

__device__ __forceinline__ void acc_pair(float& a0, float& a1, unsigned u) {
    a0 += __uint_as_float(u << 16);             // low bf16  (even dim)
    a1 += __uint_as_float(u & 0xFFFF0000u);     // high bf16 (odd dim)
}

// ---- K0: init per-bucket cursors to region bases (tiny) ----
__global__ void init_cursor_kernel(int* __restrict__ cursor) {
    int t = blockIdx.x * blockDim.x + threadIdx.x;
    if (t <= NB) cursor[t] = t * CAPB;
}

// ---- K1: fused convert(x->bf16) + hist + region-reserve + binning scatter ----
__global__ void binning_kernel(const float* __restrict__ xf,
                               ushort_t* __restrict__ xh,
                               const int* __restrict__ row,
                               const int* __restrict__ col,
                               int* __restrict__ cursor,
                               unsigned* __restrict__ packed,
                               int E, int chunk, int n4) {
    __shared__ int h[NB];
    __shared__ int lcur[NB];
    int c = blockIdx.x;
    int tid = threadIdx.x;
    // convert: grid-stride (regular cached stores: K2 gathers xh from L2)
    for (int i = c * blockDim.x + tid; i < n4; i += gridDim.x * blockDim.x) {
        float4 v = *reinterpret_cast<const float4*>(xf + (size_t)i * 4);
        ushort4 hh;
        hh.x = f32_to_bf16(v.x);
        hh.y = f32_to_bf16(v.y);
        hh.z = f32_to_bf16(v.z);
        hh.w = f32_to_bf16(v.w);
        *reinterpret_cast<ushort4*>(xh + (size_t)i * 4) = hh;
    }
    for (int b = tid; b < NB; b += blockDim.x) h[b] = 0;
    __syncthreads();
    int beg = c * chunk, end = min(beg + chunk, E);
    int nfull = (end - beg) >> 2;
    for (int g = tid; g < nfull; g += blockDim.x) {
        int4 c4 = *reinterpret_cast<const int4*>(col + beg + g * 4);
        atomicAdd(&h[c4.x >> 5], 1);
        atomicAdd(&h[c4.y >> 5], 1);
        atomicAdd(&h[c4.z >> 5], 1);
        atomicAdd(&h[c4.w >> 5], 1);
    }
    for (int e = beg + nfull * 4 + tid; e < end; e += blockDim.x)
        atomicAdd(&h[col[e] >> 5], 1);
    __syncthreads();
    for (int b = tid; b < NB; b += blockDim.x) {
        int v = h[b];
        lcur[b] = (v > 0) ? atomicAdd(&cursor[b], v) : 0;   // reserve block slice
    }
    __syncthreads();
    for (int g = tid; g < nfull; g += blockDim.x) {
        int e = beg + g * 4;
        int4 d4 = *reinterpret_cast<const int4*>(col + e);
        int4 s4 = *reinterpret_cast<const int4*>(row + e);
        int p0 = atomicAdd(&lcur[d4.x >> 5], 1);
        packed[p0] = (unsigned)s4.x | ((unsigned)(d4.x & 31) << 16);
        int p1 = atomicAdd(&lcur[d4.y >> 5], 1);
        packed[p1] = (unsigned)s4.y | ((unsigned)(d4.y & 31) << 16);
        int p2 = atomicAdd(&lcur[d4.z >> 5], 1);
        packed[p2] = (unsigned)s4.z | ((unsigned)(d4.z & 31) << 16);
        int p3 = atomicAdd(&lcur[d4.w >> 5], 1);
        packed[p3] = (unsigned)s4.w | ((unsigned)(d4.w & 31) << 16);
    }
    for (int e = beg + nfull * 4 + tid; e < end; e += blockDim.x) {
        int d = col[e];
        int p = atomicAdd(&lcur[d >> 5], 1);
        packed[p] = (unsigned)row[e] | ((unsigned)(d & 31) << 16);
    }
}

// ---- K2: single-pass per-bucket counting sort + 8-lane/row gather + mean ----
// packed register-staged (read once); out written with non-temporal stores
// so the 12.8 MB write-once stream doesn't evict xh from per-XCD L2.
template <bool BF16>
__global__ __launch_bounds__(512)
void aggregate_bucket_kernel(const float* __restrict__ xf,
                             const ushort_t* __restrict__ xh,
                             const unsigned* __restrict__ packed,
                             const int* __restrict__ cursor,
                             float* __restrict__ out) {
    __shared__ unsigned short srcs[CAP];
    __shared__ int hist[NPB];
    __shared__ int segoff[NPB];
    __shared__ int lcur[NPB];

    int b = blockIdx.x;
    int tid = threadIdx.x;                      // 0..511
    int lane = tid & 63;
    int wv = tid >> 6;                          // wave 0..7
    int g8 = lane >> 3;                         // row slot 0..7
    int o = lane & 7;                           // dim octet (dims o*8 .. o*8+7)
    int seg_beg = b * CAPB;
    int m = cursor[b] - seg_beg;                // bucket edge count (<= CAP)
    int node_base = b * NPB;
    int nnodes = min(NPB, N_NODES - node_base);

    if (tid < NPB) hist[tid] = 0;
    __syncthreads();

    // register-stage packed (2 entries/thread) + LDS histogram
    unsigned v0 = 0, v1 = 0;
    int i0 = tid, i1 = tid + 512;
    if (i0 < m) { v0 = packed[seg_beg + i0]; atomicAdd(&hist[v0 >> 16], 1); }
    if (i1 < m) { v1 = packed[seg_beg + i1]; atomicAdd(&hist[v1 >> 16], 1); }
    __syncthreads();

    if (tid < NPB) {                            // lanes 0..31 of wave 0: scan 32 bins
        int v = hist[tid];
        int incl = v;
        #pragma unroll
        for (int ofs = 1; ofs < 32; ofs <<= 1) {
            int t = __shfl_up(incl, ofs);
            if (lane >= ofs) incl += t;
        }
        segoff[tid] = incl - v;
        lcur[tid] = incl - v;
    }
    __syncthreads();

    if (i0 < m) { int p = atomicAdd(&lcur[v0 >> 16], 1); srcs[p] = (unsigned short)(v0 & 0xFFFF); }
    if (i1 < m) { int p = atomicAdd(&lcur[v1 >> 16], 1); srcs[p] = (unsigned short)(v1 & 0xFFFF); }
    __syncthreads();

    float acc[4][8];
    #pragma unroll
    for (int r = 0; r < 4; ++r)
        #pragma unroll
        for (int k = 0; k < 8; ++k) acc[r][k] = 0.0f;

    #pragma unroll
    for (int r = 0; r < 4; ++r) {
        int ln = wv * 4 + r;
        int st = segoff[ln];
        int len = hist[ln];
        int j = 0;
        for (; j + 16 <= len; j += 16) {        // 16 rows in flight per wave
            int s0 = srcs[st + j + g8];
            int s1 = srcs[st + j + 8 + g8];
            if (BF16) {
                uint4 a0 = *reinterpret_cast<const uint4*>(xh + (size_t)s0 * DIM + o * 8);
                uint4 a1 = *reinterpret_cast<const uint4*>(xh + (size_t)s1 * DIM + o * 8);
                acc_pair(acc[r][0], acc[r][1], a0.x);
                acc_pair(acc[r][2], acc[r][3], a0.y);
                acc_pair(acc[r][4], acc[r][5], a0.z);
                acc_pair(acc[r][6], acc[r][7], a0.w);
                acc_pair(acc[r][0], acc[r][1], a1.x);
                acc_pair(acc[r][2], acc[r][3], a1.y);
                acc_pair(acc[r][4], acc[r][5], a1.z);
                acc_pair(acc[r][6], acc[r][7], a1.w);
            } else {
                float4 u0 = *reinterpret_cast<const float4*>(xf + (size_t)s0 * DIM + o * 8);
                float4 u1 = *reinterpret_cast<const float4*>(xf + (size_t)s0 * DIM + o * 8 + 4);
                float4 u2 = *reinterpret_cast<const float4*>(xf + (size_t)s1 * DIM + o * 8);
                float4 u3 = *reinterpret_cast<const float4*>(xf + (size_t)s1 * DIM + o * 8 + 4);
                acc[r][0] += u0.x + u2.x; acc[r][1] += u0.y + u2.y;
                acc[r][2] += u0.z + u2.z; acc[r][3] += u0.w + u2.w;
                acc[r][4] += u1.x + u3.x; acc[r][5] += u1.y + u3.y;
                acc[r][6] += u1.z + u3.z; acc[r][7] += u1.w + u3.w;
            }
        }
        for (; j < len; j += 8) {
            if (j + g8 < len) {
                int s = srcs[st + j + g8];
                if (BF16) {
                    uint4 a0 = *reinterpret_cast<const uint4*>(xh + (size_t)s * DIM + o * 8);
                    acc_pair(acc[r][0], acc[r][1], a0.x);
                    acc_pair(acc[r][2], acc[r][3], a0.y);
                    acc_pair(acc[r][4], acc[r][5], a0.z);
                    acc_pair(acc[r][6], acc[r][7], a0.w);
                } else {
                    float4 u0 = *reinterpret_cast<const float4*>(xf + (size_t)s * DIM + o * 8);
                    float4 u1 = *reinterpret_cast<const float4*>(xf + (size_t)s * DIM + o * 8 + 4);
                    acc[r][0] += u0.x; acc[r][1] += u0.y;
                    acc[r][2] += u0.z; acc[r][3] += u0.w;
                    acc[r][4] += u1.x; acc[r][5] += u1.y;
                    acc[r][6] += u1.z; acc[r][7] += u1.w;
                }
            }
        }
    }
    __syncthreads();
    // reduce across row slots (xor 8,16,32) + mean + non-temporal store
    #pragma unroll
    for (int r = 0; r < 4; ++r) {
        int ln = wv * 4 + r;
        #pragma unroll
        for (int k = 0; k < 8; ++k) {
            acc[r][k] += __shfl_xor(acc[r][k], 8);
            acc[r][k] += __shfl_xor(acc[r][k], 16);
            acc[r][k] += __shfl_xor(acc[r][k], 32);
        }
        if (g8 == 0 && ln < nnodes) {
            int c = hist[ln];
            float inv = (c > 0) ? 1.0f / (float)c : 0.0f;
            float* op = out + (size_t)(node_base + ln) * DIM + o * 8;
            #pragma unroll
            for (int k = 0; k < 8; ++k)
                __builtin_nontemporal_store(acc[r][k] * inv, op + k);
        }
    }
}

extern "C" void kernel_launch(void* const* d_in, const int* in_sizes, int n_in,
                              void* d_out, int out_size, void* d_ws, size_t ws_size,
                              hipStream_t stream) {
    const float* x = (const float*)d_in[0];
    const int* edge_index = (const int*)d_in[1];  // [2, E] flat: row then col
    int E = in_sizes[1] / 2;
    const int* row = edge_index;
    const int* col = edge_index + E;
    float* out = (float*)d_out;

    int chunk = (((E + NCHUNK - 1) / NCHUNK) + 3) & ~3;   // multiple of 4
    int n4 = N_NODES * DIM / 4;

    // ws: cursor 1568 | packed NB*CAPB | xh N*DIM bf16
    int* cursor      = (int*)d_ws;
    unsigned* packed = (unsigned*)(cursor + 1568);
    ushort_t* xh     = (ushort_t*)(packed + (size_t)NB * CAPB);
    size_t need_bf16 = (size_t)((char*)(xh + (size_t)N_NODES * DIM) - (char*)d_ws);
    bool use_bf16 = (ws_size >= need_bf16);

    init_cursor_kernel<<<7, 256, 0, stream>>>(cursor);
    binning_kernel<<<NCHUNK, 1024, 0, stream>>>(x, xh, row, col, cursor, packed,
                                                E, chunk, use_bf16 ? n4 : 0);
    if (use_bf16)
        aggregate_bucket_kernel<true><<<NB, 512, 0, stream>>>(x, xh, packed, cursor, out);
    else
        aggregate_bucket_kernel<false><<<NB, 512, 0, stream>>>(x, xh, packed, cursor, out);
}